// Round 6
// baseline (431.546 us; speedup 1.0000x reference)
//
#include <hip/hip_runtime.h>

#define PTOT  16384
#define CCC   512
#define HHH   8
#define NK1   32                 /* k1: 512/16 k-steps */
#define NK2   16                 /* k2: 512/32 k-steps */

typedef __attribute__((ext_vector_type(4)))  float f32x4;
typedef __attribute__((ext_vector_type(16))) float f32x16;
typedef _Float16 half_t;
typedef __attribute__((ext_vector_type(8))) _Float16 f16x8;

#define MFMA16(a,b,c) __builtin_amdgcn_mfma_f32_16x16x32_f16(a,b,c,0,0,0)
#define MFMA32(a,b,c) __builtin_amdgcn_mfma_f32_32x32x16_f16(a,b,c,0,0,0)

// ---- ws plane layout (half elements) ----
#define XH_OFF   ((size_t)0)
#define XL_OFF   ((size_t)33554432)
#define ACT_OFF  ((size_t)67108864)
#define W_OFF    ((size_t)100663296)
#define WPL      ((size_t)262144)
// W plane order: 0 qh, 1 ql, 2 kh, 3 kl, 4 vh, 5 oh

// 16-row frag layout (act plane + Wo plane; k2 consumes via 16x16x32 MFMA)
__device__ __forceinline__ size_t blk_off16(int row, int col) {
    return ((size_t)((row >> 4) * 16 + (col >> 5)) << 9)
         + (size_t)(((((col >> 3) & 3) * 16) + (row & 15)) << 3) + (col & 7);
}

// ---------------------------------------------------------------------------
// k0: split fp32 -> fp16 hi/lo planes. 32-layout planes (x,Wq,Wk,Wv) are
// written lane-linear: frag f, lane l -> plane[f*512 + l*8] (fully coalesced).
// Lane l of frag (grow32, ktc) holds row = grow32*32+(l&31), k = ktc*16+(l>>5)*8.
// ---------------------------------------------------------------------------
__global__ void k0_split(const float* __restrict__ x,
                         const float* __restrict__ Wq, const float* __restrict__ Wk,
                         const float* __restrict__ Wv, const float* __restrict__ Wo,
                         half_t* __restrict__ ws)
{
    const int u = blockIdx.x * 256 + threadIdx.x;   // 4,325,376 threads
    if (u < 4194304) {                              // ---- x region ----
        const int f = u >> 6, lane6 = u & 63;
        const int grow32 = f >> 5, ktc = f & 31;
        const int row = grow32 * 32 + (lane6 & 31);
        const int k   = ktc * 16 + (lane6 >> 5) * 8;
        const float4 a = *(const float4*)(x + (size_t)row * CCC + k);
        const float4 b = *(const float4*)(x + (size_t)row * CCC + k + 4);
        const float e[8] = {a.x, a.y, a.z, a.w, b.x, b.y, b.z, b.w};
        f16x8 vh8, vl8;
        #pragma unroll
        for (int d = 0; d < 8; ++d) {
            const half_t hi = (half_t)e[d];
            vh8[d] = hi; vl8[d] = (half_t)(e[d] - (float)hi);
        }
        const size_t off = ((size_t)f << 9) + lane6 * 8;
        *(f16x8*)(ws + XH_OFF + off) = vh8;
        *(f16x8*)(ws + XL_OFF + off) = vl8;
        return;
    }
    const int u2  = u - 4194304;
    const int mat = u2 >> 15, r = u2 & 32767;
    if (mat < 3) {                                  // ---- Wq/Wk/Wv, 32-layout ----
        const float* src = (mat == 0) ? Wq : (mat == 1) ? Wk : Wv;
        const int f = r >> 6, lane6 = r & 63;
        const int grow32 = f >> 5, ktc = f & 31;
        const int row = grow32 * 32 + (lane6 & 31);
        const int k   = ktc * 16 + (lane6 >> 5) * 8;
        const float4 a = *(const float4*)(src + (size_t)row * CCC + k);
        const float4 b = *(const float4*)(src + (size_t)row * CCC + k + 4);
        const float e[8] = {a.x, a.y, a.z, a.w, b.x, b.y, b.z, b.w};
        f16x8 vh8, vl8;
        #pragma unroll
        for (int d = 0; d < 8; ++d) {
            const half_t hi = (half_t)e[d];
            vh8[d] = hi; vl8[d] = (half_t)(e[d] - (float)hi);
        }
        const size_t off = ((size_t)f << 9) + lane6 * 8;
        half_t* dh = ws + W_OFF + (size_t)(mat * 2) * WPL;
        *(f16x8*)(dh + off) = vh8;
        if (mat < 2) *(f16x8*)(dh + WPL + off) = vl8;   // lo plane for q,k only
        return;
    }
    // ---- Wo, 16-layout (round-4-verified mapping; writes coalesced) ----
    const int gr = r >> 10, v = r & 1023;
    const int ktc = v >> 6, chunk = (v >> 4) & 3, i = v & 15;
    const int row = gr * 16 + i, col = ktc * 32 + chunk * 8;
    const float4 a = *(const float4*)(Wo + (size_t)row * CCC + col);
    const float4 b = *(const float4*)(Wo + (size_t)row * CCC + col + 4);
    const float e[8] = {a.x, a.y, a.z, a.w, b.x, b.y, b.z, b.w};
    f16x8 vh8;
    #pragma unroll
    for (int d = 0; d < 8; ++d) vh8[d] = (half_t)e[d];
    *(f16x8*)(ws + W_OFF + 5 * WPL + blk_off16(row, col)) = vh8;
}

// ---------------------------------------------------------------------------
// k1: QKV projection via fp16x2 32x32x16 MFMA (Q:3,K:3,V:1) + spiking attn.
// BARRIER-FREE K-loop: every wave loads its own A/B frags global->VGPR with a
// depth-2 rotating prefetch. No LDS, no s_barrier, no manual waitcnt in loop.
// 4096 blocks x 256 thr; block = 32 tokens x 4 t (128 rows) x 1 head (64 cols).
// Wave (rg,cg): 64 rows x 32 cols. LDS (52KB) used only by the attn epilogue.
// ---------------------------------------------------------------------------
__global__ __launch_bounds__(256, 2)
void k1_mfma(const half_t* __restrict__ ws,
             const float* __restrict__ bq, const float* __restrict__ bk,
             const float* __restrict__ bv,
             half_t* __restrict__ acth)
{
    __shared__ __align__(16) char smem[52224];

    const int tid  = threadIdx.x;
    const int lane = tid & 63;
    const int wv   = tid >> 6;
    const int rg   = wv >> 1;        // row half: 64 rows
    const int cg   = wv & 1;         // col half: 32 cols
    const int l31  = lane & 31;
    const int l5   = lane >> 5;

    const int xcd  = blockIdx.x & 7;
    const int rest = blockIdx.x >> 3;
    const int h    = rest & 7;
    const int tg   = rest >> 3;
    const int p0   = (tg * 8 + xcd) * 32;

    // ---- 9 per-wave global streams (frag stride per kt = 512 halves) ----
    const half_t* pA[2][2];
    #pragma unroll
    for (int rb = 0; rb < 2; ++rb) {
        const size_t grow = (size_t)(rg * 2 + rb) * 512 + (p0 >> 5);
        pA[rb][0] = ws + XH_OFF + (grow << 14) + lane * 8;
        pA[rb][1] = ws + XL_OFF + (grow << 14) + lane * 8;
    }
    const half_t* pB[5];
    {
        const size_t grB = (size_t)(h * 2 + cg) << 14;
        #pragma unroll
        for (int s = 0; s < 5; ++s)
            pB[s] = ws + W_OFF + (size_t)s * WPL + grB + lane * 8;
    }

    // ---- accumulators (bias init; C/D: col=lane&31, row=(reg&3)+8(reg>>2)+4*l5) ----
    f32x16 accQ[2], accK[2], accV[2];
    {
        const int c0 = h * 64 + cg * 32 + l31;
        const float q0 = bq[c0], k0 = bk[c0], v0 = bv[c0];
        #pragma unroll
        for (int i = 0; i < 16; ++i) {
            accQ[0][i] = q0; accQ[1][i] = q0;
            accK[0][i] = k0; accK[1][i] = k0;
            accV[0][i] = v0; accV[1][i] = v0;
        }
    }

    f16x8 Ab[2][2][2], Bb[2][5];     // [buf][rb][pl] / [buf][plane]

#define K1_LOADSET(buf, kt) do {                                               \
    _Pragma("unroll")                                                          \
    for (int rb = 0; rb < 2; ++rb) {                                           \
        Ab[buf][rb][0] = *(const f16x8*)(pA[rb][0] + (size_t)(kt) * 512);      \
        Ab[buf][rb][1] = *(const f16x8*)(pA[rb][1] + (size_t)(kt) * 512);      \
    }                                                                          \
    _Pragma("unroll")                                                          \
    for (int s = 0; s < 5; ++s)                                                \
        Bb[buf][s] = *(const f16x8*)(pB[s] + (size_t)(kt) * 512);              \
    } while (0)

#define K1_MM(buf) do {                                                        \
    accQ[0] = MFMA32(Ab[buf][0][0], Bb[buf][0], accQ[0]);                      \
    accQ[1] = MFMA32(Ab[buf][1][0], Bb[buf][0], accQ[1]);                      \
    accK[0] = MFMA32(Ab[buf][0][0], Bb[buf][2], accK[0]);                      \
    accK[1] = MFMA32(Ab[buf][1][0], Bb[buf][2], accK[1]);                      \
    accV[0] = MFMA32(Ab[buf][0][0], Bb[buf][4], accV[0]);                      \
    accV[1] = MFMA32(Ab[buf][1][0], Bb[buf][4], accV[1]);                      \
    accQ[0] = MFMA32(Ab[buf][0][0], Bb[buf][1], accQ[0]);                      \
    accQ[1] = MFMA32(Ab[buf][1][0], Bb[buf][1], accQ[1]);                      \
    accK[0] = MFMA32(Ab[buf][0][0], Bb[buf][3], accK[0]);                      \
    accK[1] = MFMA32(Ab[buf][1][0], Bb[buf][3], accK[1]);                      \
    accQ[0] = MFMA32(Ab[buf][0][1], Bb[buf][0], accQ[0]);                      \
    accQ[1] = MFMA32(Ab[buf][1][1], Bb[buf][0], accQ[1]);                      \
    accK[0] = MFMA32(Ab[buf][0][1], Bb[buf][2], accK[0]);                      \
    accK[1] = MFMA32(Ab[buf][1][1], Bb[buf][2], accK[1]);                      \
    } while (0)

    K1_LOADSET(0, 0);
    K1_LOADSET(1, 1);
    #pragma unroll
    for (int kt = 0; kt < NK1; kt += 2) {
        K1_MM(0);
        if (kt + 2 < NK1) K1_LOADSET(0, kt + 2);
        K1_MM(1);
        if (kt + 3 < NK1) K1_LOADSET(1, kt + 3);
    }

    // ---- attention epilogue (two 16-token passes; LDS overlay) ----
    float* qa = (float*)smem;            // [64][68]
    float* ka = qa + 4352;
    float* va = qa + 8704;

    const int ar  = tid >> 2;            // 0..63 = t*16 + jj
    const int t_  = ar >> 4;
    const int jj  = ar & 15;
    const int sub = tid & 3;

    #pragma unroll
    for (int hh = 0; hh < 2; ++hh) {
        #pragma unroll
        for (int rf = 0; rf < 2; ++rf) {
            const int t = rg * 2 + rf;
            #pragma unroll
            for (int rr = 0; rr < 8; ++rr) {
                const int reg = hh * 8 + rr;
                const int j2  = (rr & 3) + 8 * (rr >> 2) + 4 * l5;   // 0..15
                const int idx = (t * 16 + j2) * 68 + cg * 32 + l31;
                qa[idx] = accQ[rf][reg];
                ka[idx] = accK[rf][reg];
                va[idx] = accV[rf][reg];
            }
        }
        __syncthreads();

        const float* qp = qa + ar * 68 + sub * 16;
        const float4 q0 = *(const float4*)(qp);
        const float4 q1 = *(const float4*)(qp + 4);
        const float4 q2 = *(const float4*)(qp + 8);
        const float4 q3 = *(const float4*)(qp + 12);
        float sc[4];
        #pragma unroll
        for (int ss = 0; ss < 4; ++ss) {
            const float* kp = ka + (ss * 16 + jj) * 68 + sub * 16;
            const float4 k0 = *(const float4*)(kp);
            const float4 k1 = *(const float4*)(kp + 4);
            const float4 k2 = *(const float4*)(kp + 8);
            const float4 k3 = *(const float4*)(kp + 12);
            float p = q0.x*k0.x + q0.y*k0.y + q0.z*k0.z + q0.w*k0.w
                    + q1.x*k1.x + q1.y*k1.y + q1.z*k1.z + q1.w*k1.w
                    + q2.x*k2.x + q2.y*k2.y + q2.z*k2.z + q2.w*k2.w
                    + q3.x*k3.x + q3.y*k3.y + q3.z*k3.z + q3.w*k3.w;
            p += __shfl_xor(p, 1);
            p += __shfl_xor(p, 2);
            sc[ss] = p;      // spike <=> (dot/8)/2 >= 1 <=> dot >= 16 (exact)
        }
        float o[16];
        #pragma unroll
        for (int d = 0; d < 16; ++d) o[d] = 0.f;
        #pragma unroll
        for (int ss = 0; ss < 4; ++ss) {
            if (sc[ss] >= 16.0f) {
                const float* vp = va + (ss * 16 + jj) * 68 + sub * 16;
                const float4 v0 = *(const float4*)(vp);
                const float4 v1 = *(const float4*)(vp + 4);
                const float4 v2 = *(const float4*)(vp + 8);
                const float4 v3 = *(const float4*)(vp + 12);
                o[0]+=v0.x; o[1]+=v0.y; o[2]+=v0.z;  o[3]+=v0.w;
                o[4]+=v1.x; o[5]+=v1.y; o[6]+=v1.z;  o[7]+=v1.w;
                o[8]+=v2.x; o[9]+=v2.y; o[10]+=v2.z; o[11]+=v2.w;
                o[12]+=v3.x;o[13]+=v3.y;o[14]+=v3.z; o[15]+=v3.w;
            }
        }
        // store act (fp16, 16-frag blocked layout for k2)
        f16x8 o0, o1;
        #pragma unroll
        for (int d = 0; d < 8; ++d) { o0[d] = (half_t)o[d]; o1[d] = (half_t)o[d + 8]; }
        const int grow = t_ * 1024 + (p0 >> 4) + hh;
        const int colb = h * 64 + sub * 16;
        const size_t cbase = ((size_t)(grow * 16 + (colb >> 5))) << 9;
        const int c0 = (colb >> 3) & 3;
        *(f16x8*)(acth + cbase + (size_t)((c0       * 16 + jj) << 3)) = o0;
        *(f16x8*)(acth + cbase + (size_t)(((c0 + 1) * 16 + jj) << 3)) = o1;
        __syncthreads();
    }
#undef K1_LOADSET
#undef K1_MM
}

// ---------------------------------------------------------------------------
// k2: out = act @ Wo^T + bo, fp16 16x16x32 MFMA. Barrier-free, zero LDS,
// depth-2 register prefetch. 2048 blocks x 256 thr; wave tile 64x64.
// ---------------------------------------------------------------------------
__global__ __launch_bounds__(256, 3)
void k2_gemm(const half_t* __restrict__ acth, const half_t* __restrict__ oh,
             const float* __restrict__ bo, float* __restrict__ out)
{
    const int tid  = threadIdx.x;
    const int lane = tid & 63;
    const int wv   = tid >> 6;
    const int wr   = wv >> 1, wc = wv & 1;
    const int l15  = lane & 15, l4 = lane >> 4;
    const int bn   = (blockIdx.x & 3) * 128;
    const int bm   = (blockIdx.x >> 2) * 128;

    const half_t* pA[4]; const half_t* pB[4];
    #pragma unroll
    for (int f = 0; f < 4; ++f) {
        pA[f] = acth + ((size_t)((bm >> 4) + wr * 4 + f) << 13) + lane * 8;
        pB[f] = oh   + ((size_t)((bn >> 4) + wc * 4 + f) << 13) + lane * 8;
    }

    f32x4 acc[4][4];
    #pragma unroll
    for (int rf = 0; rf < 4; ++rf)
        #pragma unroll
        for (int cf = 0; cf < 4; ++cf) acc[rf][cf] = f32x4{0.f, 0.f, 0.f, 0.f};

    f16x8 Ab[2][4], Bb[2][4];

#define K2_LOADSET(buf, kt) do {                                               \
    _Pragma("unroll")                                                          \
    for (int f = 0; f < 4; ++f) {                                              \
        Ab[buf][f] = *(const f16x8*)(pA[f] + (size_t)(kt) * 512);              \
        Bb[buf][f] = *(const f16x8*)(pB[f] + (size_t)(kt) * 512);              \
    }                                                                          \
    } while (0)

#define K2_MM(buf) do {                                                        \
    _Pragma("unroll")                                                          \
    for (int rf = 0; rf < 4; ++rf)                                             \
        _Pragma("unroll")                                                      \
        for (int cf = 0; cf < 4; ++cf)                                         \
            acc[rf][cf] = MFMA16(Ab[buf][rf], Bb[buf][cf], acc[rf][cf]);       \
    } while (0)

    K2_LOADSET(0, 0);
    K2_LOADSET(1, 1);
    #pragma unroll
    for (int kt = 0; kt < NK2; kt += 2) {
        K2_MM(0);
        if (kt + 2 < NK2) K2_LOADSET(0, kt + 2);
        K2_MM(1);
        if (kt + 3 < NK2) K2_LOADSET(1, kt + 3);
    }

    float bo4[4];
    #pragma unroll
    for (int cf = 0; cf < 4; ++cf) bo4[cf] = bo[bn + (wc * 4 + cf) * 16 + l15];

    #pragma unroll
    for (int rf = 0; rf < 4; ++rf) {
        const int row0 = bm + (wr * 4 + rf) * 16 + l4 * 4;
        #pragma unroll
        for (int cf = 0; cf < 4; ++cf) {
            const int col = bn + (wc * 4 + cf) * 16 + l15;
            #pragma unroll
            for (int r = 0; r < 4; ++r)
                out[(size_t)(row0 + r) * CCC + col] = acc[rf][cf][r] + bo4[cf];
        }
    }
#undef K2_LOADSET
#undef K2_MM
}

// ---------------------------------------------------------------------------
extern "C" void kernel_launch(void* const* d_in, const int* in_sizes, int n_in,
                              void* d_out, int out_size, void* d_ws, size_t ws_size,
                              hipStream_t stream)
{
    const float* x  = (const float*)d_in[0];
    const float* Wq = (const float*)d_in[1];
    const float* bq = (const float*)d_in[2];
    const float* Wk = (const float*)d_in[3];
    const float* bk = (const float*)d_in[4];
    const float* Wv = (const float*)d_in[5];
    const float* bv = (const float*)d_in[6];
    const float* Wo = (const float*)d_in[7];
    const float* bo = (const float*)d_in[8];

    half_t* ws   = (half_t*)d_ws;
    half_t* acth = ws + ACT_OFF;
    float*  out  = (float*)d_out;

    hipLaunchKernelGGL(k0_split, dim3(16896), dim3(256), 0, stream,
                       x, Wq, Wk, Wv, Wo, ws);
    hipLaunchKernelGGL(k1_mfma, dim3(4096), dim3(256), 0, stream,
                       ws, bq, bk, bv, acth);
    hipLaunchKernelGGL(k2_gemm, dim3(2048), dim3(256), 0, stream,
                       acth, ws + W_OFF + 5*WPL, bo, out);
}

// Round 7
// 337.760 us; speedup vs baseline: 1.2777x; 1.2777x over previous
//
#include <hip/hip_runtime.h>

#define PTOT  16384
#define CCC   512
#define HHH   8
#define NK1   32                 /* k1: 512/16 k-steps */
#define NK2   16                 /* k2: 512/32 k-steps */

typedef __attribute__((ext_vector_type(4)))  float f32x4;
typedef __attribute__((ext_vector_type(16))) float f32x16;
typedef _Float16 half_t;
typedef __attribute__((ext_vector_type(8))) _Float16 f16x8;

#define MFMA16(a,b,c) __builtin_amdgcn_mfma_f32_16x16x32_f16(a,b,c,0,0,0)
#define MFMA32(a,b,c) __builtin_amdgcn_mfma_f32_32x32x16_f16(a,b,c,0,0,0)

// ---- ws plane layout (half elements) ----
#define XH_OFF   ((size_t)0)
#define XL_OFF   ((size_t)33554432)
#define ACT_OFF  ((size_t)67108864)
#define W_OFF    ((size_t)100663296)
#define WPL      ((size_t)262144)
// W plane order: 0 qh, 1 ql, 2 kh, 3 kl, 4 vh, 5 oh

// 16-row frag layout (act plane + Wo plane; k2 consumes via 16x16x32 MFMA)
__device__ __forceinline__ size_t blk_off16(int row, int col) {
    return ((size_t)((row >> 4) * 16 + (col >> 5)) << 9)
         + (size_t)(((((col >> 3) & 3) * 16) + (row & 15)) << 3) + (col & 7);
}

// ---------------------------------------------------------------------------
// k0: split fp32 -> fp16 hi/lo planes. 32-layout planes (x,Wq,Wk,Wv) are
// written lane-linear: frag f, lane l -> plane[f*512 + l*8] (fully coalesced).
// Lane l of frag (grow32, ktc) holds row = grow32*32+(l&31), k = ktc*16+(l>>5)*8.
// ---------------------------------------------------------------------------
__global__ void k0_split(const float* __restrict__ x,
                         const float* __restrict__ Wq, const float* __restrict__ Wk,
                         const float* __restrict__ Wv, const float* __restrict__ Wo,
                         half_t* __restrict__ ws)
{
    const int u = blockIdx.x * 256 + threadIdx.x;   // 4,325,376 threads
    if (u < 4194304) {                              // ---- x region ----
        const int f = u >> 6, lane6 = u & 63;
        const int grow32 = f >> 5, ktc = f & 31;
        const int row = grow32 * 32 + (lane6 & 31);
        const int k   = ktc * 16 + (lane6 >> 5) * 8;
        const float4 a = *(const float4*)(x + (size_t)row * CCC + k);
        const float4 b = *(const float4*)(x + (size_t)row * CCC + k + 4);
        const float e[8] = {a.x, a.y, a.z, a.w, b.x, b.y, b.z, b.w};
        f16x8 vh8, vl8;
        #pragma unroll
        for (int d = 0; d < 8; ++d) {
            const half_t hi = (half_t)e[d];
            vh8[d] = hi; vl8[d] = (half_t)(e[d] - (float)hi);
        }
        const size_t off = ((size_t)f << 9) + lane6 * 8;
        *(f16x8*)(ws + XH_OFF + off) = vh8;
        *(f16x8*)(ws + XL_OFF + off) = vl8;
        return;
    }
    const int u2  = u - 4194304;
    const int mat = u2 >> 15, r = u2 & 32767;
    if (mat < 3) {                                  // ---- Wq/Wk/Wv, 32-layout ----
        const float* src = (mat == 0) ? Wq : (mat == 1) ? Wk : Wv;
        const int f = r >> 6, lane6 = r & 63;
        const int grow32 = f >> 5, ktc = f & 31;
        const int row = grow32 * 32 + (lane6 & 31);
        const int k   = ktc * 16 + (lane6 >> 5) * 8;
        const float4 a = *(const float4*)(src + (size_t)row * CCC + k);
        const float4 b = *(const float4*)(src + (size_t)row * CCC + k + 4);
        const float e[8] = {a.x, a.y, a.z, a.w, b.x, b.y, b.z, b.w};
        f16x8 vh8, vl8;
        #pragma unroll
        for (int d = 0; d < 8; ++d) {
            const half_t hi = (half_t)e[d];
            vh8[d] = hi; vl8[d] = (half_t)(e[d] - (float)hi);
        }
        const size_t off = ((size_t)f << 9) + lane6 * 8;
        half_t* dh = ws + W_OFF + (size_t)(mat * 2) * WPL;
        *(f16x8*)(dh + off) = vh8;
        if (mat < 2) *(f16x8*)(dh + WPL + off) = vl8;   // lo plane for q,k only
        return;
    }
    // ---- Wo, 16-layout ----
    const int gr = r >> 10, v = r & 1023;
    const int ktc = v >> 6, chunk = (v >> 4) & 3, i = v & 15;
    const int row = gr * 16 + i, col = ktc * 32 + chunk * 8;
    const float4 a = *(const float4*)(Wo + (size_t)row * CCC + col);
    const float4 b = *(const float4*)(Wo + (size_t)row * CCC + col + 4);
    const float e[8] = {a.x, a.y, a.z, a.w, b.x, b.y, b.z, b.w};
    f16x8 vh8;
    #pragma unroll
    for (int d = 0; d < 8; ++d) vh8[d] = (half_t)e[d];
    *(f16x8*)(ws + W_OFF + 5 * WPL + blk_off16(row, col)) = vh8;
}

// ---------------------------------------------------------------------------
// k1: QKV projection via fp16x2 32x32x16 MFMA (Q:3,K:3,V:1) + spiking attn.
// r5 base (LDS-staged, counted-vmcnt, 3 blocks/CU) + PHASE-SPLIT kt body:
//   phase A: 6 ds_reads (A frags + Bq) -> setprio Q-cluster (6 MFMA)
//   phase B: 3 ds_reads (Bk,Bv)        -> setprio KV-cluster (8 MFMA)
// ---------------------------------------------------------------------------
__global__ __launch_bounds__(256, 3)
void k1_mfma(const half_t* __restrict__ ws,
             const float* __restrict__ bq, const float* __restrict__ bk,
             const float* __restrict__ bv,
             half_t* __restrict__ acth)
{
    __shared__ __align__(16) char smem[52224];

    const int tid  = threadIdx.x;
    const int lane = tid & 63;
    const int wv   = tid >> 6;
    const int rg   = wv >> 1;        // row half: 64 rows
    const int cg   = wv & 1;         // col half: 32 cols
    const int l31  = lane & 31;
    const int l5   = lane >> 5;

    const int xcd  = blockIdx.x & 7;
    const int rest = blockIdx.x >> 3;
    const int h    = rest & 7;
    const int tg   = rest >> 3;
    const int p0   = (tg * 8 + xcd) * 32;

    // ---- staging issue list: 18 frags/kt/block, waves get [5,5,4,4] ----
    const int cnt  = (wv < 2) ? 5 : 4;
    const int base = (wv < 2) ? wv * 5 : 2 + wv * 4;
    const half_t* gb[5]; int lo_[5];
    #pragma unroll
    for (int ii = 0; ii < 5; ++ii) {
        const int i = base + ii;
        size_t eoff; int loff;
        if (i < 8) {            // X frag: t = i>>1, plane = i&1
            const int t = i >> 1, pl = i & 1;
            const size_t rbg = (size_t)t * 512 + (p0 >> 5);
            eoff = (pl ? XL_OFF : XH_OFF) + (rbg << 14) + lane * 8;
            loff = i * 1024;
        } else {                // W frag: s = i-8: plane = s>>1, cb = s&1
            const int s = (i - 8) & 15;
            const int plw = (s >> 1) > 4 ? 4 : (s >> 1), cb = s & 1;
            eoff = W_OFF + (size_t)plw * WPL + ((size_t)(h * 2 + cb) << 14) + lane * 8;
            loff = 8192 + s * 1024;
        }
        gb[ii] = ws + eoff;
        lo_[ii] = loff;
    }

#define K1_STAGE(buf, kt) do {                                                  \
    _Pragma("unroll")                                                           \
    for (int ii = 0; ii < 5; ++ii)                                              \
        if (ii < cnt)                                                           \
            __builtin_amdgcn_global_load_lds(                                   \
                (const __attribute__((address_space(1))) void*)(gb[ii] + (size_t)(kt) * 512), \
                (__attribute__((address_space(3))) void*)(smem + (buf) * 18432 + lo_[ii]),    \
                16, 0, 0);                                                      \
    } while (0)

    // ---- accumulators (bias init; C/D: col=lane&31, row=(reg&3)+8(reg>>2)+4*l5) ----
    f32x16 accQ[2], accK[2], accV[2];
    {
        const int c0 = h * 64 + cg * 32 + l31;
        const float q0 = bq[c0], k0 = bk[c0], v0 = bv[c0];
        #pragma unroll
        for (int i = 0; i < 16; ++i) {
            accQ[0][i] = q0; accQ[1][i] = q0;
            accK[0][i] = k0; accK[1][i] = k0;
            accV[0][i] = v0; accV[1][i] = v0;
        }
    }

    K1_STAGE(0, 0);

    #pragma unroll 2
    for (int kt = 0; kt < NK1; ++kt) {
        const int cur = kt & 1;
        if (kt + 1 < NK1) {
            K1_STAGE(cur ^ 1, kt + 1);
            if (cnt == 5) asm volatile("s_waitcnt vmcnt(5)" ::: "memory");
            else          asm volatile("s_waitcnt vmcnt(4)" ::: "memory");
        } else {
            asm volatile("s_waitcnt vmcnt(0)" ::: "memory");
        }
        __builtin_amdgcn_sched_barrier(0);
        __builtin_amdgcn_s_barrier();      // stage(kt) visible to all

        const char* bp = smem + cur * 18432;
        const int boff = 8192 + cg * 1024 + lane * 16;
        const int t0 = rg * 2, t1 = rg * 2 + 1;

        // ---- phase A: Q cluster ----
        const f16x8 Ah0 = *(const f16x8*)(bp + (t0 * 2 + 0) * 1024 + lane * 16);
        const f16x8 Al0 = *(const f16x8*)(bp + (t0 * 2 + 1) * 1024 + lane * 16);
        const f16x8 Ah1 = *(const f16x8*)(bp + (t1 * 2 + 0) * 1024 + lane * 16);
        const f16x8 Al1 = *(const f16x8*)(bp + (t1 * 2 + 1) * 1024 + lane * 16);
        const f16x8 Bqh = *(const f16x8*)(bp + boff);
        const f16x8 Bql = *(const f16x8*)(bp + boff + 2048);
        asm volatile("s_waitcnt lgkmcnt(0)" ::: "memory");
        __builtin_amdgcn_sched_barrier(0);
        __builtin_amdgcn_s_setprio(1);
        accQ[0] = MFMA32(Ah0, Bqh, accQ[0]);
        accQ[1] = MFMA32(Ah1, Bqh, accQ[1]);
        accQ[0] = MFMA32(Ah0, Bql, accQ[0]);
        accQ[1] = MFMA32(Ah1, Bql, accQ[1]);
        accQ[0] = MFMA32(Al0, Bqh, accQ[0]);
        accQ[1] = MFMA32(Al1, Bqh, accQ[1]);
        __builtin_amdgcn_s_setprio(0);
        __builtin_amdgcn_s_barrier();      // phase boundary

        // ---- phase B: K/V cluster ----
        const f16x8 Bkh = *(const f16x8*)(bp + boff + 4096);
        const f16x8 Bkl = *(const f16x8*)(bp + boff + 6144);
        const f16x8 Bvh = *(const f16x8*)(bp + boff + 8192);
        asm volatile("s_waitcnt lgkmcnt(0)" ::: "memory");
        __builtin_amdgcn_sched_barrier(0);
        __builtin_amdgcn_s_setprio(1);
        accK[0] = MFMA32(Ah0, Bkh, accK[0]);
        accK[1] = MFMA32(Ah1, Bkh, accK[1]);
        accV[0] = MFMA32(Ah0, Bvh, accV[0]);
        accV[1] = MFMA32(Ah1, Bvh, accV[1]);
        accK[0] = MFMA32(Ah0, Bkl, accK[0]);
        accK[1] = MFMA32(Ah1, Bkl, accK[1]);
        accK[0] = MFMA32(Al0, Bkh, accK[0]);
        accK[1] = MFMA32(Al1, Bkh, accK[1]);
        __builtin_amdgcn_s_setprio(0);
        __builtin_amdgcn_s_barrier();      // buf[cur] fully read
        __builtin_amdgcn_sched_barrier(0);
    }

    // ---- attention epilogue (two 16-token passes; LDS overlay) ----
    float* qa = (float*)smem;            // [64][68]
    float* ka = qa + 4352;
    float* va = qa + 8704;

    const int ar  = tid >> 2;            // 0..63 = t*16 + jj
    const int t_  = ar >> 4;
    const int jj  = ar & 15;
    const int sub = tid & 3;

    #pragma unroll
    for (int hh = 0; hh < 2; ++hh) {
        #pragma unroll
        for (int rf = 0; rf < 2; ++rf) {
            const int t = rg * 2 + rf;
            #pragma unroll
            for (int rr = 0; rr < 8; ++rr) {
                const int reg = hh * 8 + rr;
                const int j2  = (rr & 3) + 8 * (rr >> 2) + 4 * l5;   // 0..15
                const int idx = (t * 16 + j2) * 68 + cg * 32 + l31;
                qa[idx] = accQ[rf][reg];
                ka[idx] = accK[rf][reg];
                va[idx] = accV[rf][reg];
            }
        }
        __syncthreads();

        const float* qp = qa + ar * 68 + sub * 16;
        const float4 q0 = *(const float4*)(qp);
        const float4 q1 = *(const float4*)(qp + 4);
        const float4 q2 = *(const float4*)(qp + 8);
        const float4 q3 = *(const float4*)(qp + 12);
        float sc[4];
        #pragma unroll
        for (int ss = 0; ss < 4; ++ss) {
            const float* kp = ka + (ss * 16 + jj) * 68 + sub * 16;
            const float4 k0 = *(const float4*)(kp);
            const float4 k1 = *(const float4*)(kp + 4);
            const float4 k2 = *(const float4*)(kp + 8);
            const float4 k3 = *(const float4*)(kp + 12);
            float p = q0.x*k0.x + q0.y*k0.y + q0.z*k0.z + q0.w*k0.w
                    + q1.x*k1.x + q1.y*k1.y + q1.z*k1.z + q1.w*k1.w
                    + q2.x*k2.x + q2.y*k2.y + q2.z*k2.z + q2.w*k2.w
                    + q3.x*k3.x + q3.y*k3.y + q3.z*k3.z + q3.w*k3.w;
            p += __shfl_xor(p, 1);
            p += __shfl_xor(p, 2);
            sc[ss] = p;      // spike <=> (dot/8)/2 >= 1 <=> dot >= 16 (exact)
        }
        float o[16];
        #pragma unroll
        for (int d = 0; d < 16; ++d) o[d] = 0.f;
        #pragma unroll
        for (int ss = 0; ss < 4; ++ss) {
            if (sc[ss] >= 16.0f) {
                const float* vp = va + (ss * 16 + jj) * 68 + sub * 16;
                const float4 v0 = *(const float4*)(vp);
                const float4 v1 = *(const float4*)(vp + 4);
                const float4 v2 = *(const float4*)(vp + 8);
                const float4 v3 = *(const float4*)(vp + 12);
                o[0]+=v0.x; o[1]+=v0.y; o[2]+=v0.z;  o[3]+=v0.w;
                o[4]+=v1.x; o[5]+=v1.y; o[6]+=v1.z;  o[7]+=v1.w;
                o[8]+=v2.x; o[9]+=v2.y; o[10]+=v2.z; o[11]+=v2.w;
                o[12]+=v3.x;o[13]+=v3.y;o[14]+=v3.z; o[15]+=v3.w;
            }
        }
        // store act (fp16, 16-frag blocked layout for k2)
        f16x8 o0, o1;
        #pragma unroll
        for (int d = 0; d < 8; ++d) { o0[d] = (half_t)o[d]; o1[d] = (half_t)o[d + 8]; }
        const int grow = t_ * 1024 + (p0 >> 4) + hh;
        const int colb = h * 64 + sub * 16;
        const size_t cbase = ((size_t)(grow * 16 + (colb >> 5))) << 9;
        const int c0 = (colb >> 3) & 3;
        *(f16x8*)(acth + cbase + (size_t)((c0       * 16 + jj) << 3)) = o0;
        *(f16x8*)(acth + cbase + (size_t)(((c0 + 1) * 16 + jj) << 3)) = o1;
        __syncthreads();
    }
#undef K1_STAGE
}

// ---------------------------------------------------------------------------
// k2: out = act @ Wo^T + bo, fp16 16x16x32 MFMA, LDS-staged counted-vmcnt
// (round-4 proven) + setprio around the MFMA cluster.
// ---------------------------------------------------------------------------
__global__ __launch_bounds__(256, 4)
void k2_gemm(const half_t* __restrict__ acth, const half_t* __restrict__ oh,
             const float* __restrict__ bo, float* __restrict__ out)
{
    __shared__ __align__(16) char smem[32768];

    const int tid  = threadIdx.x;
    const int lane = tid & 63;
    const int wv   = tid >> 6;
    const int wr   = wv >> 1, wc = wv & 1;
    const int l15  = lane & 15, l4 = lane >> 4;
    const int bn   = (blockIdx.x & 3) * 128;
    const int bm   = (blockIdx.x >> 2) * 128;

    const half_t* gb[4]; int lo_[4];
    #pragma unroll
    for (int ii = 0; ii < 4; ++ii) {
        const int i = wv * 4 + ii;
        if (i < 8) {
            const int grow = (bm >> 4) + i;
            gb[ii] = acth + ((size_t)grow << 13) + lane * 8;
            lo_[ii] = i * 1024;
        } else {
            const int fb = i - 8;
            const int grow = (bn >> 4) + fb;
            gb[ii] = oh + ((size_t)grow << 13) + lane * 8;
            lo_[ii] = 8192 + fb * 1024;
        }
    }

#define K2_STAGE(buf, kt) do {                                                  \
    _Pragma("unroll")                                                           \
    for (int ii = 0; ii < 4; ++ii)                                              \
        __builtin_amdgcn_global_load_lds(                                       \
            (const __attribute__((address_space(1))) void*)(gb[ii] + (size_t)(kt) * 512), \
            (__attribute__((address_space(3))) void*)(smem + (buf) * 16384 + lo_[ii]),    \
            16, 0, 0);                                                          \
    } while (0)

    f32x4 acc[4][4];
    #pragma unroll
    for (int rf = 0; rf < 4; ++rf)
        #pragma unroll
        for (int cf = 0; cf < 4; ++cf) acc[rf][cf] = f32x4{0.f, 0.f, 0.f, 0.f};

    K2_STAGE(0, 0);

    #pragma unroll
    for (int kt = 0; kt < NK2; ++kt) {
        const int cur = kt & 1;
        if (kt + 1 < NK2) {
            K2_STAGE(cur ^ 1, kt + 1);
            asm volatile("s_waitcnt vmcnt(4)" ::: "memory");
        } else {
            asm volatile("s_waitcnt vmcnt(0)" ::: "memory");
        }
        __builtin_amdgcn_sched_barrier(0);
        __builtin_amdgcn_s_barrier();

        const char* bp = smem + cur * 16384;
        f16x8 B[4];
        #pragma unroll
        for (int cf = 0; cf < 4; ++cf)
            B[cf] = *(const f16x8*)(bp + 8192 + (wc * 4 + cf) * 1024 + lane * 16);
        f16x8 A[4];
        #pragma unroll
        for (int rf = 0; rf < 4; ++rf)
            A[rf] = *(const f16x8*)(bp + (wr * 4 + rf) * 1024 + lane * 16);
        asm volatile("s_waitcnt lgkmcnt(0)" ::: "memory");
        __builtin_amdgcn_sched_barrier(0);
        __builtin_amdgcn_s_setprio(1);
        #pragma unroll
        for (int rf = 0; rf < 4; ++rf)
            #pragma unroll
            for (int cf = 0; cf < 4; ++cf)
                acc[rf][cf] = MFMA16(A[rf], B[cf], acc[rf][cf]);
        __builtin_amdgcn_s_setprio(0);
        __builtin_amdgcn_s_barrier();
        __builtin_amdgcn_sched_barrier(0);
    }

    float bo4[4];
    #pragma unroll
    for (int cf = 0; cf < 4; ++cf) bo4[cf] = bo[bn + (wc * 4 + cf) * 16 + l15];

    #pragma unroll
    for (int rf = 0; rf < 4; ++rf) {
        const int row0 = bm + (wr * 4 + rf) * 16 + l4 * 4;
        #pragma unroll
        for (int cf = 0; cf < 4; ++cf) {
            const int col = bn + (wc * 4 + cf) * 16 + l15;
            #pragma unroll
            for (int r = 0; r < 4; ++r)
                out[(size_t)(row0 + r) * CCC + col] = acc[rf][cf][r] + bo4[cf];
        }
    }
#undef K2_STAGE
}

// ---------------------------------------------------------------------------
extern "C" void kernel_launch(void* const* d_in, const int* in_sizes, int n_in,
                              void* d_out, int out_size, void* d_ws, size_t ws_size,
                              hipStream_t stream)
{
    const float* x  = (const float*)d_in[0];
    const float* Wq = (const float*)d_in[1];
    const float* bq = (const float*)d_in[2];
    const float* Wk = (const float*)d_in[3];
    const float* bk = (const float*)d_in[4];
    const float* Wv = (const float*)d_in[5];
    const float* bv = (const float*)d_in[6];
    const float* Wo = (const float*)d_in[7];
    const float* bo = (const float*)d_in[8];

    half_t* ws   = (half_t*)d_ws;
    half_t* acth = ws + ACT_OFF;
    float*  out  = (float*)d_out;

    hipLaunchKernelGGL(k0_split, dim3(16896), dim3(256), 0, stream,
                       x, Wq, Wk, Wv, Wo, ws);
    hipLaunchKernelGGL(k1_mfma, dim3(4096), dim3(256), 0, stream,
                       ws, bq, bk, bv, acth);
    hipLaunchKernelGGL(k2_gemm, dim3(2048), dim3(256), 0, stream,
                       acth, ws + W_OFF + 5*WPL, bo, out);
}